// Round 14
// baseline (870.032 us; speedup 1.0000x reference)
//
#include <hip/hip_runtime.h>
#include <hip/hip_bf16.h>

#define DEV __device__ __forceinline__

constexpr int B = 16, T = 400, H = 400, V = 22000, S = 30, STEPS = 8, NG = 3;
constexpr int M  = S * B;      // 480
constexpr int H3 = 3 * H;      // 1200
constexpr int KP = 416;        // K padded to 13*32
constexpr int VP = 22016;      // V padded to 172*128
constexpr int MP = 512;        // M padded (per step slot)
constexpr int MR = STEPS * MP; // 4096
constexpr int NWP = 1280;
constexpr int NBLK = VP / 128; // 172
constexpr int NVB_S = NBLK * 2;                    // 344 per-step vocab blocks
constexpr int NCT = (H3 + 63) / 64;                // 19 gh col-tiles
constexpr int NGH = NCT * ((M + 63) / 64);         // 152 gh blocks
constexpr int GB_GH  = NVB_S;                      // 344
constexpr int GB_MRG = GB_GH + NGH;                // 496
constexpr int GB_ALL = GB_MRG + M;                 // 976
constexpr int CB_CELL = (M * H + 511) / 512;       // 375
constexpr int CB_ALL  = CB_CELL + B;               // 391
constexpr int TPAD = 416;
constexpr int PLD = 424;
constexpr long long PTS = (long long)S * B * STEPS * V;

typedef __attribute__((ext_vector_type(8))) short bfrag;
typedef __attribute__((ext_vector_type(4))) float f32x4;
typedef unsigned short u16;

DEV u16 f2bf(float x) {
  unsigned u = __float_as_uint(x);
  u += 0x7FFFu + ((u >> 16) & 1u);
  return (u16)(u >> 16);
}
DEV u16 f2bfn(float x) {
  __hip_bfloat16 h = __float2bfloat16(x);
  union { __hip_bfloat16 b; u16 u; } cv; cv.b = h; return cv.u;
}
DEV float bf2f(u16 h) { return __uint_as_float(((unsigned)h) << 16); }
DEV float sigm(float x) { return 1.0f / (1.0f + __expf(-x)); }

DEV void gload16(const u16* g, u16* l) {
  __builtin_amdgcn_global_load_lds(
      (const __attribute__((address_space(1))) void*)g,
      (__attribute__((address_space(3))) void*)l, 16, 0, 0);
}

// ---------------- merged init (KP=416) ----------------
constexpr int N_EMB = VP * KP / 256;
constexpr int N_ENC = B * 400 * TPAD / 256;
constexpr int N_W   = NWP * KP / 256;
constexpr int N_DEC = STEPS * MP * KP / 256;
constexpr int N_H0  = MP * KP / 256;
constexpr int N_ZP  = STEPS * (MP - M) * KP / 256;
constexpr int N_ZE  = MR * 16 / 256;
constexpr int N_INIT = N_EMB + N_ENC + N_W + N_DEC + N_H0 + N_ZP + N_ZE;

__global__ __launch_bounds__(256) void k_init(
    const float* __restrict__ emb, const float* __restrict__ enc,
    const float* __restrict__ Wih, const float* __restrict__ Whh,
    const float* __restrict__ semb, const float* __restrict__ ehid,
    const int* __restrict__ tgt,
    u16* __restrict__ ebf, u16* __restrict__ encbK, u16* __restrict__ encT,
    u16* __restrict__ wihH, u16* __restrict__ wihL,
    u16* __restrict__ whhH, u16* __restrict__ whhL,
    float* __restrict__ dec, u16* __restrict__ decH, u16* __restrict__ decL,
    float* __restrict__ h0F, u16* __restrict__ h0H, u16* __restrict__ h0L,
    u16* __restrict__ hAllH, u16* __restrict__ hAllL, u16* __restrict__ ebuf)
{
  int bx = blockIdx.x;
  const int tid = threadIdx.x;
  if (bx < N_EMB) {
    int i = bx * 256 + tid;
    int v = i / KP, k = i % KP;
    ebf[i] = f2bf((v < V && k < H) ? emb[(long long)v * H + k] : 0.f);
    return;
  }
  bx -= N_EMB;
  if (bx < N_ENC) {
    int i = bx * 256 + tid;
    int c = i % TPAD, r = (i / TPAD) % 400, b = i / (TPAD * 400);
    encbK[i] = f2bf((c < H) ? enc[((size_t)b * T + r) * H + c] : 0.f);
    encT[i]  = f2bf((c < T) ? enc[((size_t)b * T + c) * H + r] : 0.f);
    return;
  }
  bx -= N_ENC;
  if (bx < N_W) {
    int i = bx * 256 + tid;
    int n = i / KP, k = i % KP;
    float v1 = (n < H3 && k < H) ? Wih[n * H + k] : 0.f;
    u16 h1 = f2bf(v1);
    wihH[i] = h1; wihL[i] = f2bf(v1 - bf2f(h1));
    float v2 = (n < H3 && k < H) ? Whh[n * H + k] : 0.f;
    u16 h2 = f2bf(v2);
    whhH[i] = h2; whhL[i] = f2bf(v2 - bf2f(h2));
    return;
  }
  bx -= N_W;
  if (bx < N_DEC) {
    int i = bx * 256 + tid;
    int k = i % KP, m = (i / KP) % MP, s = i / (KP * MP);
    float val = 0.f;
    if (m < M && k < H) {
      int slot = m / B, b = m % B;
      if (s == 0) val = semb[slot * H + k];
      else        val = emb[(long long)tgt[(b * S + slot) * STEPS + (s - 1)] * H + k];
      dec[((long long)s * M + m) * H + k] = val;
    }
    u16 hi = f2bf(val);
    decH[i] = hi; decL[i] = f2bf(val - bf2f(hi));
    return;
  }
  bx -= N_DEC;
  if (bx < N_H0) {
    int i = bx * 256 + tid;
    int k = i % KP, m = i / KP;
    float val = (m < M && k < H) ? ehid[(m % B) * H + k] : 0.f;
    if (m < M && k < H) h0F[m * H + k] = val;
    u16 hi = f2bf(val);
    h0H[i] = hi; h0L[i] = f2bf(val - bf2f(hi));
    return;
  }
  bx -= N_H0;
  if (bx < N_ZP) {
    int i = bx * 256 + tid;
    int k = i % KP;
    int row = M + (i / KP) % (MP - M);
    int s = i / (KP * (MP - M));
    size_t idx = ((size_t)s * MP + row) * KP + k;
    hAllH[idx] = 0; hAllL[idx] = 0;
    return;
  }
  bx -= N_ZP;
  {
    int i = bx * 256 + tid;
    int row = i / 16, col = V + (i % 16);
    ebuf[(size_t)row * VP + col] = 0;
  }
}

// ---------------- 64x64-tile SPLIT GEMM (gi batched, gh step 0) ----------------
__global__ __launch_bounds__(256) void k_gemm64s(
    const u16* __restrict__ Ahi, const u16* __restrict__ Alo,
    const u16* __restrict__ Bmh, const u16* __restrict__ Bml,
    const float* __restrict__ bias, float* __restrict__ C,
    int Mvalid, int Nvalid, int Cstride)
{
  __shared__ u16 BsH[64 * 32], BsL[64 * 32];
  const int tid = threadIdx.x;
  const int wave = tid >> 6, lane = tid & 63;
  const int wm = wave >> 1, wn = wave & 1;
  const int n0 = blockIdx.x * 64;
  const int m0 = blockIdx.y * 64;
  const int lrow = lane & 15;
  const int c16 = lane >> 4;
  const int srow = tid >> 2;
  const int sg = (tid & 3) ^ (srow & 3);
  f32x4 acc[2][2] = {};

  const u16* aH = Ahi + (size_t)(m0 + wm * 32 + lrow) * KP + c16 * 8;
  const u16* aL = Alo + (size_t)(m0 + wm * 32 + lrow) * KP + c16 * 8;
  const u16* bHs = Bmh + (size_t)(n0 + srow) * KP + sg * 8;
  const u16* bLs = Bml + (size_t)(n0 + srow) * KP + sg * 8;
  u16* lBH = BsH + wave * 512;
  u16* lBL = BsL + wave * 512;

  for (int kk = 0; kk < KP / 32; ++kk) {
    const int kb = kk * 32;
    gload16(bHs + kb, lBH);
    gload16(bLs + kb, lBL);
    __syncthreads();
    bfrag a0h = *(const bfrag*)(aH + kb);
    bfrag a1h = *(const bfrag*)(aH + 16 * KP + kb);
    bfrag a0l = *(const bfrag*)(aL + kb);
    bfrag a1l = *(const bfrag*)(aL + 16 * KP + kb);
#pragma unroll
    for (int nn = 0; nn < 2; ++nn) {
      const int br = wn * 32 + nn * 16 + lrow;
      const int goff = br * 32 + ((c16 ^ (br & 3)) << 3);
      bfrag bh = *(const bfrag*)&BsH[goff];
      bfrag bl = *(const bfrag*)&BsL[goff];
      acc[0][nn] = __builtin_amdgcn_mfma_f32_16x16x32_bf16(a0h, bh, acc[0][nn], 0, 0, 0);
      acc[1][nn] = __builtin_amdgcn_mfma_f32_16x16x32_bf16(a1h, bh, acc[1][nn], 0, 0, 0);
      acc[0][nn] = __builtin_amdgcn_mfma_f32_16x16x32_bf16(a0h, bl, acc[0][nn], 0, 0, 0);
      acc[1][nn] = __builtin_amdgcn_mfma_f32_16x16x32_bf16(a1h, bl, acc[1][nn], 0, 0, 0);
      acc[0][nn] = __builtin_amdgcn_mfma_f32_16x16x32_bf16(a0l, bh, acc[0][nn], 0, 0, 0);
      acc[1][nn] = __builtin_amdgcn_mfma_f32_16x16x32_bf16(a1l, bh, acc[1][nn], 0, 0, 0);
    }
    __syncthreads();
  }
  const int orow = (lane >> 4) << 2, ocol = lane & 15;
#pragma unroll
  for (int am = 0; am < 2; ++am) {
#pragma unroll
    for (int nn = 0; nn < 2; ++nn) {
      const int gn = n0 + wn * 32 + nn * 16 + ocol;
      if (gn >= Nvalid) continue;
      const float badd = bias[gn];
#pragma unroll
      for (int r = 0; r < 4; ++r) {
        const int gm = m0 + wm * 32 + am * 16 + orow + r;
        if (gm < Mvalid) C[(long long)gm * Cstride + gn] = acc[am][nn][r] + badd;
      }
    }
  }
}

// ---------------- k_bigv: [vocab(vS) ∥ gh(ghS) ∥ merge(mS)] ----------------
// vocab/gh bodies verbatim from R12; merge body verbatim from R12's k_merge.
__global__ __launch_bounds__(512) void k_bigv(
    const u16* __restrict__ hAllH, const u16* __restrict__ hAllL,
    const u16* __restrict__ ebf, u16* __restrict__ ebuf,
    const u16* __restrict__ whhH, const u16* __restrict__ whhL,
    const float* __restrict__ bhh, float* __restrict__ gh,
    const float* __restrict__ pgenB, const float* __restrict__ attnB,
    const int* __restrict__ story, float* __restrict__ out,
    int vS, int ghS, int mS)
{
  __shared__ union SMU {
    u16 vb[4][4096];                                   // vocab staging (32 KB)
    struct { u16 bh[64 * 32]; u16 bl[64 * 32]; } g;    // gh staging
    float red8[8];                                     // merge
  } sm;
  const int bx = blockIdx.x;
  const int tid = threadIdx.x;
  const int wave = tid >> 6, lane = tid & 63;

  if (bx < GB_GH) {
    // ================= vocab branch =================
    if (vS < 0) return;
    const u16* hPrevH = hAllH + (size_t)vS * MP * KP;
    const long long Rbase = (long long)vS * MP;
    const int bxs = (bx & 7) * (NVB_S / 8) + (bx >> 3);
    const int nb = bxs >> 1;
    const int m0 = (bxs & 1) * 256;
    const int n0 = nb * 128;
    const int wm = wave >> 1, wn = wave & 1;
    const int lrow = lane & 15;
    const int c16 = lane >> 4;
    const int srow = tid >> 2;
    const int sg = (tid & 3) ^ (srow & 3);
    f32x4 acc[4][4] = {};

    const u16* aBase = hPrevH + (size_t)(m0 + wm * 64 + lrow) * KP + c16 * 8;
    const u16* bS = ebf + (size_t)(n0 + srow) * KP + sg * 8;

    gload16(bS + 0,  &sm.vb[0][wave * 512]);
    gload16(bS + 32, &sm.vb[1][wave * 512]);
    int cur = 0;
#pragma unroll 1
    for (int p = 0; p < 7; ++p) {
      const int kb = p * 64;
      bfrag a[4][2];
#pragma unroll
      for (int r = 0; r < 4; ++r) {
        a[r][0] = *(const bfrag*)(aBase + r * 16 * KP + kb);
        if (p < 6) a[r][1] = *(const bfrag*)(aBase + r * 16 * KP + kb + 32);
      }
      if (p < 5) {
        gload16(bS + kb + 64, &sm.vb[(cur ^ 1) * 2 + 0][wave * 512]);
        gload16(bS + kb + 96, &sm.vb[(cur ^ 1) * 2 + 1][wave * 512]);
        asm volatile("s_waitcnt vmcnt(10)" ::: "memory");
      } else if (p == 5) {
        gload16(bS + kb + 64, &sm.vb[(cur ^ 1) * 2 + 0][wave * 512]);
        asm volatile("s_waitcnt vmcnt(9)" ::: "memory");
      } else {
        asm volatile("s_waitcnt vmcnt(4)" ::: "memory");
      }
      __builtin_amdgcn_sched_barrier(0);
      __builtin_amdgcn_s_barrier();
      {
        const u16* Bb = sm.vb[cur * 2 + 0];
        bfrag bfv[4];
#pragma unroll
        for (int nn = 0; nn < 4; ++nn) {
          const int brr = wn * 64 + nn * 16 + lrow;
          bfv[nn] = *(const bfrag*)&Bb[brr * 32 + ((c16 ^ (brr & 3)) << 3)];
        }
#pragma unroll
        for (int nn = 0; nn < 4; ++nn) {
#pragma unroll
          for (int r = 0; r < 4; ++r)
            acc[r][nn] = __builtin_amdgcn_mfma_f32_16x16x32_bf16(a[r][0], bfv[nn], acc[r][nn], 0, 0, 0);
        }
      }
      if (p < 6) {
        const u16* Bb = sm.vb[cur * 2 + 1];
        bfrag bfv[4];
#pragma unroll
        for (int nn = 0; nn < 4; ++nn) {
          const int brr = wn * 64 + nn * 16 + lrow;
          bfv[nn] = *(const bfrag*)&Bb[brr * 32 + ((c16 ^ (brr & 3)) << 3)];
        }
#pragma unroll
        for (int nn = 0; nn < 4; ++nn) {
#pragma unroll
          for (int r = 0; r < 4; ++r)
            acc[r][nn] = __builtin_amdgcn_mfma_f32_16x16x32_bf16(a[r][1], bfv[nn], acc[r][nn], 0, 0, 0);
        }
      }
      __builtin_amdgcn_sched_barrier(0);
      __builtin_amdgcn_s_barrier();
      __builtin_amdgcn_sched_barrier(0);
      cur ^= 1;
    }

    const int orow = (lane >> 4) << 2, ocol = lane & 15;
#pragma unroll
    for (int af = 0; af < 4; ++af) {
#pragma unroll
      for (int r = 0; r < 4; ++r) {
        const int rl = m0 + wm * 64 + af * 16 + orow + r;
        if (rl >= M) continue;
        const size_t R = (size_t)(Rbase + rl);
#pragma unroll
        for (int nn = 0; nn < 4; ++nn) {
          const int gn = n0 + wn * 64 + nn * 16 + ocol;
          if (gn < V) ebuf[R * VP + gn] = f2bfn(__expf(acc[af][nn][r]));
        }
      }
    }
  } else if (bx < GB_MRG) {
    // ================= gh GEMM branch =================
    if (ghS < 0) return;
    const u16* hPrevH = hAllH + (size_t)(ghS - 1) * MP * KP;
    const u16* hPrevL = hAllL + (size_t)(ghS - 1) * MP * KP;
    const int gb = bx - GB_GH;
    const int n0 = (gb % NCT) * 64;
    const int m0 = (gb / NCT) * 64;
    const bool act = tid < 256;
    const int wm = wave >> 1, wn = wave & 1;
    const int lrow = lane & 15;
    const int c16 = lane >> 4;
    const int srow = tid >> 2;
    const int sg = (tid & 3) ^ (srow & 3);
    f32x4 acc[2][2] = {};

    const u16* aH = hPrevH + (size_t)(m0 + (wm & 1) * 32 + lrow) * KP + c16 * 8;
    const u16* aL = hPrevL + (size_t)(m0 + (wm & 1) * 32 + lrow) * KP + c16 * 8;
    const u16* bHs = whhH + (size_t)(n0 + (srow & 63)) * KP + sg * 8;
    const u16* bLs = whhL + (size_t)(n0 + (srow & 63)) * KP + sg * 8;
    u16* lBH = sm.g.bh + (wave & 3) * 512;
    u16* lBL = sm.g.bl + (wave & 3) * 512;

    for (int kk = 0; kk < KP / 32; ++kk) {
      const int kb = kk * 32;
      if (act) {
        gload16(bHs + kb, lBH);
        gload16(bLs + kb, lBL);
      }
      __syncthreads();
      if (act) {
        bfrag a0h = *(const bfrag*)(aH + kb);
        bfrag a1h = *(const bfrag*)(aH + 16 * KP + kb);
        bfrag a0l = *(const bfrag*)(aL + kb);
        bfrag a1l = *(const bfrag*)(aL + 16 * KP + kb);
#pragma unroll
        for (int nn = 0; nn < 2; ++nn) {
          const int br = wn * 32 + nn * 16 + lrow;
          const int goff = br * 32 + ((c16 ^ (br & 3)) << 3);
          bfrag bh = *(const bfrag*)&sm.g.bh[goff];
          bfrag bl = *(const bfrag*)&sm.g.bl[goff];
          acc[0][nn] = __builtin_amdgcn_mfma_f32_16x16x32_bf16(a0h, bh, acc[0][nn], 0, 0, 0);
          acc[1][nn] = __builtin_amdgcn_mfma_f32_16x16x32_bf16(a1h, bh, acc[1][nn], 0, 0, 0);
          acc[0][nn] = __builtin_amdgcn_mfma_f32_16x16x32_bf16(a0h, bl, acc[0][nn], 0, 0, 0);
          acc[1][nn] = __builtin_amdgcn_mfma_f32_16x16x32_bf16(a1h, bl, acc[1][nn], 0, 0, 0);
          acc[0][nn] = __builtin_amdgcn_mfma_f32_16x16x32_bf16(a0l, bh, acc[0][nn], 0, 0, 0);
          acc[1][nn] = __builtin_amdgcn_mfma_f32_16x16x32_bf16(a1l, bh, acc[1][nn], 0, 0, 0);
        }
      }
      __syncthreads();
    }
    if (act) {
      const int orow = (lane >> 4) << 2, ocol = lane & 15;
#pragma unroll
      for (int am = 0; am < 2; ++am) {
#pragma unroll
        for (int nn = 0; nn < 2; ++nn) {
          const int gn = n0 + wn * 32 + nn * 16 + ocol;
          if (gn >= H3) continue;
          const float badd = bhh[gn];
#pragma unroll
          for (int r = 0; r < 4; ++r) {
            const int gm = m0 + wm * 32 + am * 16 + orow + r;
            if (gm < M) gh[(long long)gm * H3 + gn] = acc[am][nn][r] + badd;
          }
        }
      }
    }
  } else {
    // ================= merge branch (480 blocks, step mS) =================
    if (mS < 0) return;
    const int s = mS;
    const int m = bx - GB_MRG;
    const int b = m % B;
    const size_t R = (size_t)s * MP + m;
    const u16* erow = ebuf + R * VP;
    bfrag ch[6];
    float sum = 0.f;
#pragma unroll
    for (int j = 0; j < 6; ++j) {
      const int c = j * 512 + tid;
      if (c < VP / 8) {
        ch[j] = *(const bfrag*)(erow + (size_t)c * 8);
#pragma unroll
        for (int e = 0; e < 8; ++e) sum += bf2f((u16)ch[j][e]);
      }
    }
#pragma unroll
    for (int off = 32; off; off >>= 1) sum += __shfl_xor(sum, off);
    if (lane == 0) sm.red8[wave] = sum;
    __syncthreads();
    float Sv = 0.f;
#pragma unroll
    for (int j = 0; j < 8; ++j) Sv += sm.red8[j];
    const float pg = pgenB[s * M + m];
    const float scale = pg / Sv;
    float* orow = out + ((size_t)m * STEPS + s) * V;
#pragma unroll
    for (int j = 0; j < 6; ++j) {
      const int c = j * 512 + tid;
      if (c < V / 8) {
        f32x4 w0, w1;
#pragma unroll
        for (int e = 0; e < 4; ++e) {
          w0[e] = bf2f((u16)ch[j][e]) * scale;
          w1[e] = bf2f((u16)ch[j][4 + e]) * scale;
        }
        *(f32x4*)(orow + (size_t)c * 8) = w0;
        *(f32x4*)(orow + (size_t)c * 8 + 4) = w1;
      }
    }
    __syncthreads();
    const float om = 1.f - pg;
    for (int t = tid; t < T; t += 512) {
      float a = attnB[((size_t)s * M + m) * T + t];
      if (a != 0.f) atomicAdd(orow + story[b * T + t], om * a);
    }
  }
}

// ---------------- k_cellx: [GRU cell(docell) ∥ attn(aS)] ----------------
struct SMatt {
  u16 P[32 * PLD];
  float partm[32][4];
  float parts[32][4];
  float rowred[32];
  float part2[32][4][4];
};

__global__ __launch_bounds__(512) void k_cellx(
    const float* __restrict__ gi_s, const float* __restrict__ gh,
    const float* __restrict__ hprevF, float* __restrict__ hcurF,
    u16* __restrict__ hHc, u16* __restrict__ hLc,
    const u16* __restrict__ hAllH, const u16* __restrict__ hAllL,
    const float* __restrict__ hallF,
    const u16* __restrict__ encbK, const u16* __restrict__ encT,
    const int* __restrict__ lens, const float* __restrict__ dec,
    const float* __restrict__ Wr, const float* __restrict__ br,
    const float* __restrict__ Wg, const float* __restrict__ bg,
    float* __restrict__ attnB, float* __restrict__ pgenB, float* __restrict__ out,
    int docell, int aS)
{
  __shared__ SMatt sm;
  const int bx = blockIdx.x;
  const int tid = threadIdx.x;
  const int wave = tid >> 6, lane = tid & 63;

  if (bx < CB_CELL) {
    // ================= cell branch (elementwise) =================
    if (!docell) return;
    int i = bx * 512 + tid;
    if (i >= M * H) return;
    int k = i % H, m = i / H;
    float ir = gi_s[m * H3 + k],         hr = gh[m * H3 + k];
    float iz = gi_s[m * H3 + H + k],     hz = gh[m * H3 + H + k];
    float in_ = gi_s[m * H3 + 2*H + k],  hn = gh[m * H3 + 2*H + k];
    float rr = sigm(ir + hr);
    float z = sigm(iz + hz);
    float n = tanhf(in_ + rr * hn);
    float hv = (1.f - z) * n + z * hprevF[i];
    hcurF[i] = hv;
    u16 hb = f2bf(hv);
    hHc[m * KP + k] = hb;
    hLc[m * KP + k] = f2bf(hv - bf2f(hb));
  } else {
    // ================= attn branch (16 blocks, step aS) =================
    if (aS < 0) return;
    const int s = aS;
    const int b = bx - CB_CELL;
    const int mt = wave & 1;
    const int wg = wave >> 1;
    const int lrow = lane & 15;
    const int c16 = lane >> 4;
    const int len = lens[b];
    const int rbase = mt * 16 + c16 * 4;

    for (int idx = tid; idx < 32 * 24; idx += 512)
      sm.P[(idx / 24) * PLD + 400 + (idx % 24)] = 0;

    f32x4 acc[7] = {};
    {
      const size_t arow = (size_t)s * MP + (size_t)(mt * 16 + lrow) * B + b;
      const u16* aHp = hAllH + arow * KP + c16 * 8;
      const u16* aLp = hAllL + arow * KP + c16 * 8;
      const u16* bBase = encbK + (size_t)b * 400 * TPAD + c16 * 8;
      for (int kk = 0; kk < 13; ++kk) {
        bfrag ah = *(const bfrag*)(aHp + kk * 32);
        bfrag al = *(const bfrag*)(aLp + kk * 32);
#pragma unroll
        for (int i = 0; i < 7; ++i) {
          const int jt = wg + 4 * i;
          if (jt < 25) {
            bfrag bv = *(const bfrag*)(bBase + (size_t)(jt * 16 + lrow) * TPAD + kk * 32);
            acc[i] = __builtin_amdgcn_mfma_f32_16x16x32_bf16(ah, bv, acc[i], 0, 0, 0);
            acc[i] = __builtin_amdgcn_mfma_f32_16x16x32_bf16(al, bv, acc[i], 0, 0, 0);
          }
        }
      }
    }

    {
      float pm[4] = {-1e30f, -1e30f, -1e30f, -1e30f};
#pragma unroll
      for (int i = 0; i < 7; ++i) {
        const int jt = wg + 4 * i;
        if (jt >= 25) continue;
        const int t = jt * 16 + lrow;
        const bool ok = t < len;
#pragma unroll
        for (int rr = 0; rr < 4; ++rr) pm[rr] = fmaxf(pm[rr], ok ? acc[i][rr] : -1e30f);
      }
#pragma unroll
      for (int d = 1; d < 16; d <<= 1) {
#pragma unroll
        for (int rr = 0; rr < 4; ++rr) pm[rr] = fmaxf(pm[rr], __shfl_xor(pm[rr], d));
      }
      if (lrow == 0) {
#pragma unroll
        for (int rr = 0; rr < 4; ++rr) sm.partm[rbase + rr][wg] = pm[rr];
      }
    }
    __syncthreads();
    if (tid < 32)
      sm.rowred[tid] = fmaxf(fmaxf(sm.partm[tid][0], sm.partm[tid][1]),
                             fmaxf(sm.partm[tid][2], sm.partm[tid][3]));
    __syncthreads();
    float Mx[4];
#pragma unroll
    for (int rr = 0; rr < 4; ++rr) Mx[rr] = sm.rowred[rbase + rr];
    {
      float ps[4] = {0.f, 0.f, 0.f, 0.f};
#pragma unroll
      for (int i = 0; i < 7; ++i) {
        const int jt = wg + 4 * i;
        if (jt >= 25) continue;
        const int t = jt * 16 + lrow;
        const bool ok = t < len;
#pragma unroll
        for (int rr = 0; rr < 4; ++rr) {
          float e = ok ? __expf(acc[i][rr] - Mx[rr]) : 0.f;
          acc[i][rr] = e;
          ps[rr] += e;
        }
      }
#pragma unroll
      for (int d = 1; d < 16; d <<= 1) {
#pragma unroll
        for (int rr = 0; rr < 4; ++rr) ps[rr] += __shfl_xor(ps[rr], d);
      }
      if (lrow == 0) {
#pragma unroll
        for (int rr = 0; rr < 4; ++rr) sm.parts[rbase + rr][wg] = ps[rr];
      }
    }
    __syncthreads();
    if (tid < 32)
      sm.rowred[tid] = sm.parts[tid][0] + sm.parts[tid][1] + sm.parts[tid][2] + sm.parts[tid][3];
    __syncthreads();
    {
      float inv[4];
#pragma unroll
      for (int rr = 0; rr < 4; ++rr) inv[rr] = 1.f / sm.rowred[rbase + rr];
#pragma unroll
      for (int i = 0; i < 7; ++i) {
        const int jt = wg + 4 * i;
        if (jt >= 25) continue;
        const int t = jt * 16 + lrow;
#pragma unroll
        for (int rr = 0; rr < 4; ++rr) {
          const int row = rbase + rr;
          const float p = acc[i][rr] * inv[rr];
          sm.P[row * PLD + t] = f2bfn(p);
          if (row < 30) attnB[((size_t)s * M + row * B + b) * T + t] = p;
        }
      }
    }
    __syncthreads();

    f32x4 acc2[7] = {};
    {
      const u16* bBase = encT + (size_t)b * 400 * TPAD + c16 * 8;
      const u16* aP = sm.P + (mt * 16 + lrow) * PLD + c16 * 8;
      for (int kk = 0; kk < 13; ++kk) {
        bfrag ap = *(const bfrag*)(aP + kk * 32);
#pragma unroll
        for (int i = 0; i < 7; ++i) {
          const int jk = wg + 4 * i;
          if (jk < 25) {
            bfrag bv = *(const bfrag*)(bBase + (size_t)(jk * 16 + lrow) * TPAD + kk * 32);
            acc2[i] = __builtin_amdgcn_mfma_f32_16x16x32_bf16(ap, bv, acc2[i], 0, 0, 0);
          }
        }
      }
    }
    {
      float pw[4] = {0.f, 0.f, 0.f, 0.f};
      float pg0[4] = {0.f, 0.f, 0.f, 0.f};
      float pg1[4] = {0.f, 0.f, 0.f, 0.f};
      float pg2[4] = {0.f, 0.f, 0.f, 0.f};
      const bool do_g = (s == 0);
#pragma unroll
      for (int i = 0; i < 7; ++i) {
        const int jk = wg + 4 * i;
        if (jk >= 25) continue;
        const int k = jk * 16 + lrow;
        const float wr = Wr[H + k];
        float w0 = 0.f, w1 = 0.f, w2 = 0.f;
        if (do_g) { w0 = Wg[k]; w1 = Wg[H + k]; w2 = Wg[2 * H + k]; }
#pragma unroll
        for (int rr = 0; rr < 4; ++rr) {
          const float v = acc2[i][rr];
          pw[rr] = fmaf(v, wr, pw[rr]);
          if (do_g) {
            pg0[rr] = fmaf(v, w0, pg0[rr]);
            pg1[rr] = fmaf(v, w1, pg1[rr]);
            pg2[rr] = fmaf(v, w2, pg2[rr]);
          }
        }
      }
#pragma unroll
      for (int d = 1; d < 16; d <<= 1) {
#pragma unroll
        for (int rr = 0; rr < 4; ++rr) {
          pw[rr] += __shfl_xor(pw[rr], d);
          pg0[rr] += __shfl_xor(pg0[rr], d);
          pg1[rr] += __shfl_xor(pg1[rr], d);
          pg2[rr] += __shfl_xor(pg2[rr], d);
        }
      }
      if (lrow == 0) {
#pragma unroll
        for (int rr = 0; rr < 4; ++rr) {
          sm.part2[rbase + rr][wg][0] = pw[rr];
          sm.part2[rbase + rr][wg][1] = pg0[rr];
          sm.part2[rbase + rr][wg][2] = pg1[rr];
          sm.part2[rbase + rr][wg][3] = pg2[rr];
        }
      }
    }
    __syncthreads();

    if (tid < 480) {
      const int row = tid >> 4;
      const int l16 = tid & 15;
      const int m = row * B + b;
      const float* hF = hallF + ((size_t)s * M + m) * H;
      const float* dF = dec + ((size_t)s * M + m) * H;
      float p = 0.f;
      for (int j = 0; j < 25; ++j) {
        const int k = l16 + 16 * j;
        p += hF[k] * Wr[k] + dF[k] * Wr[2 * H + k];
      }
#pragma unroll
      for (int d = 1; d < 16; d <<= 1) p += __shfl_xor(p, d);
      if (l16 == 0) {
        float cw = sm.part2[row][0][0] + sm.part2[row][1][0] +
                   sm.part2[row][2][0] + sm.part2[row][3][0];
        pgenB[s * M + m] = sigm(p + cw + br[0]);
      }
      if (s == 0 && l16 < NG) {
        float gv = sm.part2[row][0][1 + l16] + sm.part2[row][1][1 + l16] +
                   sm.part2[row][2][1 + l16] + sm.part2[row][3][1 + l16];
        out[PTS + (long long)m * NG + l16] = gv + bg[l16];
      }
    }
  }
}

// ---------------- launch ----------------

extern "C" void kernel_launch(void* const* d_in, const int* in_sizes, int n_in,
                              void* d_out, int out_size, void* d_ws, size_t ws_size,
                              hipStream_t stream) {
  (void)in_sizes; (void)n_in; (void)out_size; (void)ws_size;
  const float* emb  = (const float*)d_in[0];
  const float* Wih  = (const float*)d_in[1];
  const float* Whh  = (const float*)d_in[2];
  const float* bih  = (const float*)d_in[3];
  const float* bhh  = (const float*)d_in[4];
  const float* Wr   = (const float*)d_in[5];
  const float* br   = (const float*)d_in[6];
  const float* Wg   = (const float*)d_in[7];
  const float* bg   = (const float*)d_in[8];
  const float* semb = (const float*)d_in[9];
  const float* ehid = (const float*)d_in[10];
  const float* enc  = (const float*)d_in[11];
  const int*   lens = (const int*)d_in[12];
  const int*   story= (const int*)d_in[13];
  const int*   tgt  = (const int*)d_in[14];
  float* out = (float*)d_out;

  char* w = (char*)d_ws;
  size_t off = 0;
  auto alloc = [&](size_t n) -> void* {
    void* p = w + off;
    off = (off + n + 255) & ~(size_t)255;
    return p;
  };
  u16* ebf    = (u16*)alloc((size_t)VP * KP * 2);
  u16* wihH   = (u16*)alloc((size_t)NWP * KP * 2);
  u16* wihL   = (u16*)alloc((size_t)NWP * KP * 2);
  u16* whhH   = (u16*)alloc((size_t)NWP * KP * 2);
  u16* whhL   = (u16*)alloc((size_t)NWP * KP * 2);
  u16* decH   = (u16*)alloc((size_t)STEPS * MP * KP * 2);
  u16* decL   = (u16*)alloc((size_t)STEPS * MP * KP * 2);
  float* dec  = (float*)alloc((size_t)STEPS * M * H * 4);
  float* h0F  = (float*)alloc((size_t)M * H * 4);
  u16* h0H    = (u16*)alloc((size_t)MP * KP * 2);
  u16* h0L    = (u16*)alloc((size_t)MP * KP * 2);
  u16* hAllH  = (u16*)alloc((size_t)MR * KP * 2);
  u16* hAllL  = (u16*)alloc((size_t)MR * KP * 2);
  float* hallF= (float*)alloc((size_t)STEPS * M * H * 4);
  float* gi   = (float*)alloc((size_t)MR * H3 * 4);
  float* gh   = (float*)alloc((size_t)M * H3 * 4);
  float* attnB= (float*)alloc((size_t)STEPS * M * T * 4);
  float* pgenB= (float*)alloc((size_t)STEPS * M * 4);
  u16* ebuf   = (u16*)alloc((size_t)MR * VP * 2);
  u16* encbK  = (u16*)alloc((size_t)B * 400 * TPAD * 2);
  u16* encT   = (u16*)alloc((size_t)B * 400 * TPAD * 2);

  k_init<<<N_INIT, 256, 0, stream>>>(emb, enc, Wih, Whh, semb, ehid, tgt,
      ebf, encbK, encT, wihH, wihL, whhH, whhL, dec, decH, decL,
      h0F, h0H, h0L, hAllH, hAllL, ebuf);
  // all-steps gi = dec @ Wih^T + bih
  k_gemm64s<<<dim3(NCT, MR / 64), 256, 0, stream>>>(
      decH, decL, wihH, wihL, bih, gi, MR, H3, H3);

  // step 0 spine
  k_gemm64s<<<dim3(NCT, (M + 63) / 64), 256, 0, stream>>>(
      h0H, h0L, whhH, whhL, bhh, gh, M, H3, H3);
  k_cellx<<<CB_ALL, 512, 0, stream>>>(
      gi, gh, h0F, hallF, hAllH, hAllL,
      hAllH, hAllL, hallF, encbK, encT, lens, dec, Wr, br, Wg, bg,
      attnB, pgenB, out, 1, -1);

  // steps 1..7: bigv{vocab(s-1) ∥ gh(s) ∥ merge(s-2)} then cellx{cell(s) ∥ attn(s-1)}
  for (int s = 1; s < STEPS; ++s) {
    k_bigv<<<GB_ALL, 512, 0, stream>>>(
        hAllH, hAllL, ebf, ebuf, whhH, whhL, bhh, gh,
        pgenB, attnB, story, out, s - 1, s, s - 2);
    k_cellx<<<CB_ALL, 512, 0, stream>>>(
        gi + (size_t)s * MP * H3, gh, hallF + (size_t)(s - 1) * M * H,
        hallF + (size_t)s * M * H,
        hAllH + (size_t)s * MP * KP, hAllL + (size_t)s * MP * KP,
        hAllH, hAllL, hallF, encbK, encT, lens, dec, Wr, br, Wg, bg,
        attnB, pgenB, out, 1, s - 1);
  }
  // tail1: vocab(7) ∥ merge(6)
  k_bigv<<<GB_ALL, 512, 0, stream>>>(
      hAllH, hAllL, ebf, ebuf, whhH, whhL, bhh, gh,
      pgenB, attnB, story, out, 7, -1, 6);
  // tail2: attn(7)
  k_cellx<<<CB_ALL, 512, 0, stream>>>(
      gi, gh, h0F, hallF, hAllH, hAllL,
      hAllH, hAllL, hallF, encbK, encT, lens, dec, Wr, br, Wg, bg,
      attnB, pgenB, out, 0, 7);
  // tail3: merge(7)
  k_bigv<<<GB_ALL, 512, 0, stream>>>(
      hAllH, hAllL, ebf, ebuf, whhH, whhL, bhh, gh,
      pgenB, attnB, story, out, -1, -1, 7);
}

// Round 15
// 555.002 us; speedup vs baseline: 1.5676x; 1.5676x over previous
//
#include <hip/hip_runtime.h>
#include <hip/hip_bf16.h>

#define DEV __device__ __forceinline__

constexpr int B = 16, T = 400, H = 400, V = 22000, S = 30, STEPS = 8, NG = 3;
constexpr int M  = S * B;      // 480
constexpr int H3 = 3 * H;      // 1200
constexpr int KP = 416;        // K padded to 13*32
constexpr int VP = 22016;      // V padded to 172*128
constexpr int MP = 512;        // M padded (per step slot)
constexpr int MR = STEPS * MP; // 4096
constexpr int NWP = 1280;
constexpr int NBLK = VP / 128; // 172
constexpr int NVB_S = NBLK * 2;                    // 344 per-step vocab blocks
constexpr int NCT = (H3 + 63) / 64;                // 19 gh col-tiles
constexpr int NGH = NCT * ((M + 63) / 64);         // 152 gh blocks
constexpr int TPAD = 416;
constexpr int PLD = 424;
constexpr long long PTS = (long long)S * B * STEPS * V;

typedef __attribute__((ext_vector_type(8))) short bfrag;
typedef __attribute__((ext_vector_type(4))) float f32x4;
typedef unsigned short u16;

DEV u16 f2bf(float x) {
  unsigned u = __float_as_uint(x);
  u += 0x7FFFu + ((u >> 16) & 1u);
  return (u16)(u >> 16);
}
DEV u16 f2bfn(float x) {
  __hip_bfloat16 h = __float2bfloat16(x);
  union { __hip_bfloat16 b; u16 u; } cv; cv.b = h; return cv.u;
}
DEV float bf2f(u16 h) { return __uint_as_float(((unsigned)h) << 16); }
DEV float sigm(float x) { return 1.0f / (1.0f + __expf(-x)); }

DEV void gload16(const u16* g, u16* l) {
  __builtin_amdgcn_global_load_lds(
      (const __attribute__((address_space(1))) void*)g,
      (__attribute__((address_space(3))) void*)l, 16, 0, 0);
}

// ---------------- merged init (KP=416) ----------------
constexpr int N_EMB = VP * KP / 256;
constexpr int N_ENC = B * 400 * TPAD / 256;
constexpr int N_W   = NWP * KP / 256;
constexpr int N_DEC = STEPS * MP * KP / 256;
constexpr int N_H0  = MP * KP / 256;
constexpr int N_ZP  = STEPS * (MP - M) * KP / 256;
constexpr int N_ZE  = MR * 16 / 256;
constexpr int N_INIT = N_EMB + N_ENC + N_W + N_DEC + N_H0 + N_ZP + N_ZE;

__global__ __launch_bounds__(256) void k_init(
    const float* __restrict__ emb, const float* __restrict__ enc,
    const float* __restrict__ Wih, const float* __restrict__ Whh,
    const float* __restrict__ semb, const float* __restrict__ ehid,
    const int* __restrict__ tgt,
    u16* __restrict__ ebf, u16* __restrict__ encbK, u16* __restrict__ encT,
    u16* __restrict__ wihH, u16* __restrict__ wihL,
    u16* __restrict__ whhH, u16* __restrict__ whhL,
    float* __restrict__ dec, u16* __restrict__ decH, u16* __restrict__ decL,
    float* __restrict__ h0F, u16* __restrict__ h0H, u16* __restrict__ h0L,
    u16* __restrict__ hAllH, u16* __restrict__ hAllL, u16* __restrict__ ebuf)
{
  int bx = blockIdx.x;
  const int tid = threadIdx.x;
  if (bx < N_EMB) {
    int i = bx * 256 + tid;
    int v = i / KP, k = i % KP;
    ebf[i] = f2bf((v < V && k < H) ? emb[(long long)v * H + k] : 0.f);
    return;
  }
  bx -= N_EMB;
  if (bx < N_ENC) {
    int i = bx * 256 + tid;
    int c = i % TPAD, r = (i / TPAD) % 400, b = i / (TPAD * 400);
    encbK[i] = f2bf((c < H) ? enc[((size_t)b * T + r) * H + c] : 0.f);
    encT[i]  = f2bf((c < T) ? enc[((size_t)b * T + c) * H + r] : 0.f);
    return;
  }
  bx -= N_ENC;
  if (bx < N_W) {
    int i = bx * 256 + tid;
    int n = i / KP, k = i % KP;
    float v1 = (n < H3 && k < H) ? Wih[n * H + k] : 0.f;
    u16 h1 = f2bf(v1);
    wihH[i] = h1; wihL[i] = f2bf(v1 - bf2f(h1));
    float v2 = (n < H3 && k < H) ? Whh[n * H + k] : 0.f;
    u16 h2 = f2bf(v2);
    whhH[i] = h2; whhL[i] = f2bf(v2 - bf2f(h2));
    return;
  }
  bx -= N_W;
  if (bx < N_DEC) {
    int i = bx * 256 + tid;
    int k = i % KP, m = (i / KP) % MP, s = i / (KP * MP);
    float val = 0.f;
    if (m < M && k < H) {
      int slot = m / B, b = m % B;
      if (s == 0) val = semb[slot * H + k];
      else        val = emb[(long long)tgt[(b * S + slot) * STEPS + (s - 1)] * H + k];
      dec[((long long)s * M + m) * H + k] = val;
    }
    u16 hi = f2bf(val);
    decH[i] = hi; decL[i] = f2bf(val - bf2f(hi));
    return;
  }
  bx -= N_DEC;
  if (bx < N_H0) {
    int i = bx * 256 + tid;
    int k = i % KP, m = i / KP;
    float val = (m < M && k < H) ? ehid[(m % B) * H + k] : 0.f;
    if (m < M && k < H) h0F[m * H + k] = val;
    u16 hi = f2bf(val);
    h0H[i] = hi; h0L[i] = f2bf(val - bf2f(hi));
    return;
  }
  bx -= N_H0;
  if (bx < N_ZP) {
    int i = bx * 256 + tid;
    int k = i % KP;
    int row = M + (i / KP) % (MP - M);
    int s = i / (KP * (MP - M));
    size_t idx = ((size_t)s * MP + row) * KP + k;
    hAllH[idx] = 0; hAllL[idx] = 0;
    return;
  }
  bx -= N_ZP;
  {
    int i = bx * 256 + tid;
    int row = i / 16, col = V + (i % 16);
    ebuf[(size_t)row * VP + col] = 0;
  }
}

// ---------------- 64x64-tile SPLIT GEMM (gi batched, gh step 0) ----------------
__global__ __launch_bounds__(256) void k_gemm64s(
    const u16* __restrict__ Ahi, const u16* __restrict__ Alo,
    const u16* __restrict__ Bmh, const u16* __restrict__ Bml,
    const float* __restrict__ bias, float* __restrict__ C,
    int Mvalid, int Nvalid, int Cstride)
{
  __shared__ u16 BsH[64 * 32], BsL[64 * 32];
  const int tid = threadIdx.x;
  const int wave = tid >> 6, lane = tid & 63;
  const int wm = wave >> 1, wn = wave & 1;
  const int n0 = blockIdx.x * 64;
  const int m0 = blockIdx.y * 64;
  const int lrow = lane & 15;
  const int c16 = lane >> 4;
  const int srow = tid >> 2;
  const int sg = (tid & 3) ^ (srow & 3);
  f32x4 acc[2][2] = {};

  const u16* aH = Ahi + (size_t)(m0 + wm * 32 + lrow) * KP + c16 * 8;
  const u16* aL = Alo + (size_t)(m0 + wm * 32 + lrow) * KP + c16 * 8;
  const u16* bHs = Bmh + (size_t)(n0 + srow) * KP + sg * 8;
  const u16* bLs = Bml + (size_t)(n0 + srow) * KP + sg * 8;
  u16* lBH = BsH + wave * 512;
  u16* lBL = BsL + wave * 512;

  for (int kk = 0; kk < KP / 32; ++kk) {
    const int kb = kk * 32;
    gload16(bHs + kb, lBH);
    gload16(bLs + kb, lBL);
    __syncthreads();
    bfrag a0h = *(const bfrag*)(aH + kb);
    bfrag a1h = *(const bfrag*)(aH + 16 * KP + kb);
    bfrag a0l = *(const bfrag*)(aL + kb);
    bfrag a1l = *(const bfrag*)(aL + 16 * KP + kb);
#pragma unroll
    for (int nn = 0; nn < 2; ++nn) {
      const int br = wn * 32 + nn * 16 + lrow;
      const int goff = br * 32 + ((c16 ^ (br & 3)) << 3);
      bfrag bh = *(const bfrag*)&BsH[goff];
      bfrag bl = *(const bfrag*)&BsL[goff];
      acc[0][nn] = __builtin_amdgcn_mfma_f32_16x16x32_bf16(a0h, bh, acc[0][nn], 0, 0, 0);
      acc[1][nn] = __builtin_amdgcn_mfma_f32_16x16x32_bf16(a1h, bh, acc[1][nn], 0, 0, 0);
      acc[0][nn] = __builtin_amdgcn_mfma_f32_16x16x32_bf16(a0h, bl, acc[0][nn], 0, 0, 0);
      acc[1][nn] = __builtin_amdgcn_mfma_f32_16x16x32_bf16(a1h, bl, acc[1][nn], 0, 0, 0);
      acc[0][nn] = __builtin_amdgcn_mfma_f32_16x16x32_bf16(a0l, bh, acc[0][nn], 0, 0, 0);
      acc[1][nn] = __builtin_amdgcn_mfma_f32_16x16x32_bf16(a1l, bh, acc[1][nn], 0, 0, 0);
    }
    __syncthreads();
  }
  const int orow = (lane >> 4) << 2, ocol = lane & 15;
#pragma unroll
  for (int am = 0; am < 2; ++am) {
#pragma unroll
    for (int nn = 0; nn < 2; ++nn) {
      const int gn = n0 + wn * 32 + nn * 16 + ocol;
      if (gn >= Nvalid) continue;
      const float badd = bias[gn];
#pragma unroll
      for (int r = 0; r < 4; ++r) {
        const int gm = m0 + wm * 32 + am * 16 + orow + r;
        if (gm < Mvalid) C[(long long)gm * Cstride + gn] = acc[am][nn][r] + badd;
      }
    }
  }
}

// ---------------- GRU cell ----------------
__global__ __launch_bounds__(512) void k_cell(const float* __restrict__ gi_s,
                                              const float* __restrict__ gh,
                                              const float* __restrict__ hprevF,
                                              float* __restrict__ hcurF,
                                              u16* __restrict__ hHc, u16* __restrict__ hLc) {
  int i = blockIdx.x * 512 + threadIdx.x;
  if (i >= M * H) return;
  int k = i % H, m = i / H;
  float ir = gi_s[m * H3 + k],         hr = gh[m * H3 + k];
  float iz = gi_s[m * H3 + H + k],     hz = gh[m * H3 + H + k];
  float in_ = gi_s[m * H3 + 2*H + k],  hn = gh[m * H3 + 2*H + k];
  float rr = sigm(ir + hr);
  float z = sigm(iz + hz);
  float n = tanhf(in_ + rr * hn);
  float hv = (1.f - z) * n + z * hprevF[i];
  hcurF[i] = hv;
  u16 hb = f2bf(hv);
  hHc[m * KP + k] = hb;
  hLc[m * KP + k] = f2bf(hv - bf2f(hb));
}

// ---------------- k_bigv: [vocab(step prev, 344 blocks) ∥ gh GEMM(next, 152 blocks)] ----------------
__global__ __launch_bounds__(512) void k_bigv(
    const u16* __restrict__ hPrevH, const u16* __restrict__ hPrevL,
    const u16* __restrict__ ebf, u16* __restrict__ ebuf, long long Rbase,
    const u16* __restrict__ whhH, const u16* __restrict__ whhL,
    const float* __restrict__ bhh, float* __restrict__ gh)
{
  __shared__ union SMU {
    u16 vb[4][4096];                            // vocab: [dbuf*2+sub][128 x 32]
    struct { u16 bh[64 * 32]; u16 bl[64 * 32]; } g;  // gh staging
  } sm;
  const int bx = blockIdx.x;
  const int tid = threadIdx.x;
  const int wave = tid >> 6, lane = tid & 63;

  if (bx < NVB_S) {
    // ================= vocab branch (BK=64 pipeline) =================
    const int bxs = (bx & 7) * (NVB_S / 8) + (bx >> 3);   // bijective XCD swizzle
    const int nb = bxs >> 1;
    const int m0 = (bxs & 1) * 256;
    const int n0 = nb * 128;
    const int wm = wave >> 1, wn = wave & 1;
    const int lrow = lane & 15;
    const int c16 = lane >> 4;
    const int srow = tid >> 2;
    const int sg = (tid & 3) ^ (srow & 3);
    f32x4 acc[4][4] = {};

    const u16* aBase = hPrevH + (size_t)(m0 + wm * 64 + lrow) * KP + c16 * 8;
    const u16* bS = ebf + (size_t)(n0 + srow) * KP + sg * 8;

    gload16(bS + 0,  &sm.vb[0][wave * 512]);
    gload16(bS + 32, &sm.vb[1][wave * 512]);
    int cur = 0;
#pragma unroll 1
    for (int p = 0; p < 7; ++p) {       // 6 full BK=64 phases + 1 BK=32 tail
      const int kb = p * 64;
      bfrag a[4][2];
#pragma unroll
      for (int r = 0; r < 4; ++r) {
        a[r][0] = *(const bfrag*)(aBase + r * 16 * KP + kb);
        if (p < 6) a[r][1] = *(const bfrag*)(aBase + r * 16 * KP + kb + 32);
      }
      if (p < 5) {
        gload16(bS + kb + 64, &sm.vb[(cur ^ 1) * 2 + 0][wave * 512]);
        gload16(bS + kb + 96, &sm.vb[(cur ^ 1) * 2 + 1][wave * 512]);
        asm volatile("s_waitcnt vmcnt(10)" ::: "memory");
      } else if (p == 5) {
        gload16(bS + kb + 64, &sm.vb[(cur ^ 1) * 2 + 0][wave * 512]);
        asm volatile("s_waitcnt vmcnt(9)" ::: "memory");
      } else {
        asm volatile("s_waitcnt vmcnt(4)" ::: "memory");
      }
      __builtin_amdgcn_sched_barrier(0);
      __builtin_amdgcn_s_barrier();
      {
        const u16* Bb = sm.vb[cur * 2 + 0];
        bfrag bfv[4];
#pragma unroll
        for (int nn = 0; nn < 4; ++nn) {
          const int brr = wn * 64 + nn * 16 + lrow;
          bfv[nn] = *(const bfrag*)&Bb[brr * 32 + ((c16 ^ (brr & 3)) << 3)];
        }
#pragma unroll
        for (int nn = 0; nn < 4; ++nn) {
#pragma unroll
          for (int r = 0; r < 4; ++r)
            acc[r][nn] = __builtin_amdgcn_mfma_f32_16x16x32_bf16(a[r][0], bfv[nn], acc[r][nn], 0, 0, 0);
        }
      }
      if (p < 6) {
        const u16* Bb = sm.vb[cur * 2 + 1];
        bfrag bfv[4];
#pragma unroll
        for (int nn = 0; nn < 4; ++nn) {
          const int brr = wn * 64 + nn * 16 + lrow;
          bfv[nn] = *(const bfrag*)&Bb[brr * 32 + ((c16 ^ (brr & 3)) << 3)];
        }
#pragma unroll
        for (int nn = 0; nn < 4; ++nn) {
#pragma unroll
          for (int r = 0; r < 4; ++r)
            acc[r][nn] = __builtin_amdgcn_mfma_f32_16x16x32_bf16(a[r][1], bfv[nn], acc[r][nn], 0, 0, 0);
        }
      }
      __builtin_amdgcn_sched_barrier(0);
      __builtin_amdgcn_s_barrier();
      __builtin_amdgcn_sched_barrier(0);
      cur ^= 1;
    }

    // epilogue: e = exp(logit) -> bf16 (normalized in k_merge)
    const int orow = (lane >> 4) << 2, ocol = lane & 15;
#pragma unroll
    for (int af = 0; af < 4; ++af) {
#pragma unroll
      for (int r = 0; r < 4; ++r) {
        const int rl = m0 + wm * 64 + af * 16 + orow + r;   // local row 0..511
        if (rl >= M) continue;                              // pad rows 480..511
        const size_t R = (size_t)(Rbase + rl);
#pragma unroll
        for (int nn = 0; nn < 4; ++nn) {
          const int gn = n0 + wn * 64 + nn * 16 + ocol;
          if (gn < V) ebuf[R * VP + gn] = f2bfn(__expf(acc[af][nn][r]));
        }
      }
    }
  } else {
    // ================= gh GEMM branch (threads <256 active; uniform barriers) =================
    const int gb = bx - NVB_S;
    const int n0 = (gb % NCT) * 64;
    const int m0 = (gb / NCT) * 64;
    const bool act = tid < 256;
    const int wm = wave >> 1, wn = wave & 1;
    const int lrow = lane & 15;
    const int c16 = lane >> 4;
    const int srow = tid >> 2;
    const int sg = (tid & 3) ^ (srow & 3);
    f32x4 acc[2][2] = {};

    const u16* aH = hPrevH + (size_t)(m0 + (wm & 1) * 32 + lrow) * KP + c16 * 8;
    const u16* aL = hPrevL + (size_t)(m0 + (wm & 1) * 32 + lrow) * KP + c16 * 8;
    const u16* bHs = whhH + (size_t)(n0 + (srow & 63)) * KP + sg * 8;
    const u16* bLs = whhL + (size_t)(n0 + (srow & 63)) * KP + sg * 8;
    u16* lBH = sm.g.bh + (wave & 3) * 512;
    u16* lBL = sm.g.bl + (wave & 3) * 512;

    for (int kk = 0; kk < KP / 32; ++kk) {
      const int kb = kk * 32;
      if (act) {
        gload16(bHs + kb, lBH);
        gload16(bLs + kb, lBL);
      }
      __syncthreads();
      if (act) {
        bfrag a0h = *(const bfrag*)(aH + kb);
        bfrag a1h = *(const bfrag*)(aH + 16 * KP + kb);
        bfrag a0l = *(const bfrag*)(aL + kb);
        bfrag a1l = *(const bfrag*)(aL + 16 * KP + kb);
#pragma unroll
        for (int nn = 0; nn < 2; ++nn) {
          const int br = wn * 32 + nn * 16 + lrow;
          const int goff = br * 32 + ((c16 ^ (br & 3)) << 3);
          bfrag bh = *(const bfrag*)&sm.g.bh[goff];
          bfrag bl = *(const bfrag*)&sm.g.bl[goff];
          acc[0][nn] = __builtin_amdgcn_mfma_f32_16x16x32_bf16(a0h, bh, acc[0][nn], 0, 0, 0);
          acc[1][nn] = __builtin_amdgcn_mfma_f32_16x16x32_bf16(a1h, bh, acc[1][nn], 0, 0, 0);
          acc[0][nn] = __builtin_amdgcn_mfma_f32_16x16x32_bf16(a0h, bl, acc[0][nn], 0, 0, 0);
          acc[1][nn] = __builtin_amdgcn_mfma_f32_16x16x32_bf16(a1h, bl, acc[1][nn], 0, 0, 0);
          acc[0][nn] = __builtin_amdgcn_mfma_f32_16x16x32_bf16(a0l, bh, acc[0][nn], 0, 0, 0);
          acc[1][nn] = __builtin_amdgcn_mfma_f32_16x16x32_bf16(a1l, bh, acc[1][nn], 0, 0, 0);
        }
      }
      __syncthreads();
    }
    if (act) {
      const int orow = (lane >> 4) << 2, ocol = lane & 15;
#pragma unroll
      for (int am = 0; am < 2; ++am) {
#pragma unroll
        for (int nn = 0; nn < 2; ++nn) {
          const int gn = n0 + wn * 32 + nn * 16 + ocol;
          if (gn >= H3) continue;
          const float badd = bhh[gn];
#pragma unroll
          for (int r = 0; r < 4; ++r) {
            const int gm = m0 + wm * 32 + am * 16 + orow + r;
            if (gm < M) gh[(long long)gm * H3 + gn] = acc[am][nn][r] + badd;
          }
        }
      }
    }
  }
}

// ---------------- k_attn: MFMA attention, one block per (s,b) ----------------
struct SMatt {
  u16 P[32 * PLD];
  float partm[32][4];
  float parts[32][4];
  float rowred[32];
  float part2[32][4][4];
};

__global__ __launch_bounds__(512) void k_attn(
    const u16* __restrict__ hAllH, const u16* __restrict__ hAllL,
    const float* __restrict__ hallF,
    const u16* __restrict__ encbK, const u16* __restrict__ encT,
    const int* __restrict__ lens, const float* __restrict__ dec,
    const float* __restrict__ Wr, const float* __restrict__ br,
    const float* __restrict__ Wg, const float* __restrict__ bg,
    float* __restrict__ attnB, float* __restrict__ pgenB, float* __restrict__ out)
{
  __shared__ SMatt sm;
  const int s = blockIdx.x >> 4;
  const int b = blockIdx.x & 15;
  const int tid = threadIdx.x;
  const int wave = tid >> 6, lane = tid & 63;
  const int mt = wave & 1;
  const int wg = wave >> 1;
  const int lrow = lane & 15;
  const int c16 = lane >> 4;
  const int len = lens[b];
  const int rbase = mt * 16 + c16 * 4;

  for (int idx = tid; idx < 32 * 24; idx += 512)
    sm.P[(idx / 24) * PLD + 400 + (idx % 24)] = 0;

  f32x4 acc[7] = {};
  {
    const size_t arow = (size_t)s * MP + (size_t)(mt * 16 + lrow) * B + b;
    const u16* aHp = hAllH + arow * KP + c16 * 8;
    const u16* aLp = hAllL + arow * KP + c16 * 8;
    const u16* bBase = encbK + (size_t)b * 400 * TPAD + c16 * 8;
    for (int kk = 0; kk < 13; ++kk) {
      bfrag ah = *(const bfrag*)(aHp + kk * 32);
      bfrag al = *(const bfrag*)(aLp + kk * 32);
#pragma unroll
      for (int i = 0; i < 7; ++i) {
        const int jt = wg + 4 * i;
        if (jt < 25) {
          bfrag bv = *(const bfrag*)(bBase + (size_t)(jt * 16 + lrow) * TPAD + kk * 32);
          acc[i] = __builtin_amdgcn_mfma_f32_16x16x32_bf16(ah, bv, acc[i], 0, 0, 0);
          acc[i] = __builtin_amdgcn_mfma_f32_16x16x32_bf16(al, bv, acc[i], 0, 0, 0);
        }
      }
    }
  }

  {
    float pm[4] = {-1e30f, -1e30f, -1e30f, -1e30f};
#pragma unroll
    for (int i = 0; i < 7; ++i) {
      const int jt = wg + 4 * i;
      if (jt >= 25) continue;
      const int t = jt * 16 + lrow;
      const bool ok = t < len;
#pragma unroll
      for (int rr = 0; rr < 4; ++rr) pm[rr] = fmaxf(pm[rr], ok ? acc[i][rr] : -1e30f);
    }
#pragma unroll
    for (int d = 1; d < 16; d <<= 1) {
#pragma unroll
      for (int rr = 0; rr < 4; ++rr) pm[rr] = fmaxf(pm[rr], __shfl_xor(pm[rr], d));
    }
    if (lrow == 0) {
#pragma unroll
      for (int rr = 0; rr < 4; ++rr) sm.partm[rbase + rr][wg] = pm[rr];
    }
  }
  __syncthreads();
  if (tid < 32)
    sm.rowred[tid] = fmaxf(fmaxf(sm.partm[tid][0], sm.partm[tid][1]),
                           fmaxf(sm.partm[tid][2], sm.partm[tid][3]));
  __syncthreads();
  float Mx[4];
#pragma unroll
  for (int rr = 0; rr < 4; ++rr) Mx[rr] = sm.rowred[rbase + rr];
  {
    float ps[4] = {0.f, 0.f, 0.f, 0.f};
#pragma unroll
    for (int i = 0; i < 7; ++i) {
      const int jt = wg + 4 * i;
      if (jt >= 25) continue;
      const int t = jt * 16 + lrow;
      const bool ok = t < len;
#pragma unroll
      for (int rr = 0; rr < 4; ++rr) {
        float e = ok ? __expf(acc[i][rr] - Mx[rr]) : 0.f;
        acc[i][rr] = e;
        ps[rr] += e;
      }
    }
#pragma unroll
    for (int d = 1; d < 16; d <<= 1) {
#pragma unroll
      for (int rr = 0; rr < 4; ++rr) ps[rr] += __shfl_xor(ps[rr], d);
    }
    if (lrow == 0) {
#pragma unroll
      for (int rr = 0; rr < 4; ++rr) sm.parts[rbase + rr][wg] = ps[rr];
    }
  }
  __syncthreads();
  if (tid < 32)
    sm.rowred[tid] = sm.parts[tid][0] + sm.parts[tid][1] + sm.parts[tid][2] + sm.parts[tid][3];
  __syncthreads();
  {
    float inv[4];
#pragma unroll
    for (int rr = 0; rr < 4; ++rr) inv[rr] = 1.f / sm.rowred[rbase + rr];
#pragma unroll
    for (int i = 0; i < 7; ++i) {
      const int jt = wg + 4 * i;
      if (jt >= 25) continue;
      const int t = jt * 16 + lrow;
#pragma unroll
      for (int rr = 0; rr < 4; ++rr) {
        const int row = rbase + rr;
        const float p = acc[i][rr] * inv[rr];
        sm.P[row * PLD + t] = f2bfn(p);
        if (row < 30) attnB[((size_t)s * M + row * B + b) * T + t] = p;
      }
    }
  }
  __syncthreads();

  f32x4 acc2[7] = {};
  {
    const u16* bBase = encT + (size_t)b * 400 * TPAD + c16 * 8;
    const u16* aP = sm.P + (mt * 16 + lrow) * PLD + c16 * 8;
    for (int kk = 0; kk < 13; ++kk) {
      bfrag ap = *(const bfrag*)(aP + kk * 32);
#pragma unroll
      for (int i = 0; i < 7; ++i) {
        const int jk = wg + 4 * i;
        if (jk < 25) {
          bfrag bv = *(const bfrag*)(bBase + (size_t)(jk * 16 + lrow) * TPAD + kk * 32);
          acc2[i] = __builtin_amdgcn_mfma_f32_16x16x32_bf16(ap, bv, acc2[i], 0, 0, 0);
        }
      }
    }
  }
  {
    float pw[4] = {0.f, 0.f, 0.f, 0.f};
    float pg0[4] = {0.f, 0.f, 0.f, 0.f};
    float pg1[4] = {0.f, 0.f, 0.f, 0.f};
    float pg2[4] = {0.f, 0.f, 0.f, 0.f};
    const bool do_g = (s == 0);
#pragma unroll
    for (int i = 0; i < 7; ++i) {
      const int jk = wg + 4 * i;
      if (jk >= 25) continue;
      const int k = jk * 16 + lrow;
      const float wr = Wr[H + k];
      float w0 = 0.f, w1 = 0.f, w2 = 0.f;
      if (do_g) { w0 = Wg[k]; w1 = Wg[H + k]; w2 = Wg[2 * H + k]; }
#pragma unroll
      for (int rr = 0; rr < 4; ++rr) {
        const float v = acc2[i][rr];
        pw[rr] = fmaf(v, wr, pw[rr]);
        if (do_g) {
          pg0[rr] = fmaf(v, w0, pg0[rr]);
          pg1[rr] = fmaf(v, w1, pg1[rr]);
          pg2[rr] = fmaf(v, w2, pg2[rr]);
        }
      }
    }
#pragma unroll
    for (int d = 1; d < 16; d <<= 1) {
#pragma unroll
      for (int rr = 0; rr < 4; ++rr) {
        pw[rr] += __shfl_xor(pw[rr], d);
        pg0[rr] += __shfl_xor(pg0[rr], d);
        pg1[rr] += __shfl_xor(pg1[rr], d);
        pg2[rr] += __shfl_xor(pg2[rr], d);
      }
    }
    if (lrow == 0) {
#pragma unroll
      for (int rr = 0; rr < 4; ++rr) {
        sm.part2[rbase + rr][wg][0] = pw[rr];
        sm.part2[rbase + rr][wg][1] = pg0[rr];
        sm.part2[rbase + rr][wg][2] = pg1[rr];
        sm.part2[rbase + rr][wg][3] = pg2[rr];
      }
    }
  }
  __syncthreads();

  if (tid < 480) {
    const int row = tid >> 4;
    const int l16 = tid & 15;
    const int m = row * B + b;
    const float* hF = hallF + ((size_t)s * M + m) * H;
    const float* dF = dec + ((size_t)s * M + m) * H;
    float p = 0.f;
    for (int j = 0; j < 25; ++j) {
      const int k = l16 + 16 * j;
      p += hF[k] * Wr[k] + dF[k] * Wr[2 * H + k];
    }
#pragma unroll
    for (int d = 1; d < 16; d <<= 1) p += __shfl_xor(p, d);
    if (l16 == 0) {
      float cw = sm.part2[row][0][0] + sm.part2[row][1][0] +
                 sm.part2[row][2][0] + sm.part2[row][3][0];
      pgenB[s * M + m] = sigm(p + cw + br[0]);
    }
    if (s == 0 && l16 < NG) {
      float gv = sm.part2[row][0][1 + l16] + sm.part2[row][1][1 + l16] +
                 sm.part2[row][2][1 + l16] + sm.part2[row][3][1 + l16];
      out[PTS + (long long)m * NG + l16] = gv + bg[l16];
    }
  }
}

// ---------------- k_merge: row-sum from ebuf, scale, write, scatter ----------------
__global__ __launch_bounds__(512) void k_merge(
    const u16* __restrict__ ebuf, const float* __restrict__ pgenB,
    const float* __restrict__ attnB, const int* __restrict__ story,
    float* __restrict__ out)
{
  const int bxi = blockIdx.x;
  const int s = bxi / M, m = bxi % M, b = m % B;
  const size_t R = (size_t)s * MP + m;
  const int tid = threadIdx.x;
  const int wave = tid >> 6, lane = tid & 63;
  __shared__ float red8[8];
  const u16* erow = ebuf + R * VP;
  bfrag ch[6];
  float sum = 0.f;
#pragma unroll
  for (int j = 0; j < 6; ++j) {
    const int c = j * 512 + tid;
    if (c < VP / 8) {
      ch[j] = *(const bfrag*)(erow + (size_t)c * 8);
#pragma unroll
      for (int e = 0; e < 8; ++e) sum += bf2f((u16)ch[j][e]);
    }
  }
#pragma unroll
  for (int off = 32; off; off >>= 1) sum += __shfl_xor(sum, off);
  if (lane == 0) red8[wave] = sum;
  __syncthreads();
  float Sv = 0.f;
#pragma unroll
  for (int j = 0; j < 8; ++j) Sv += red8[j];
  const float pg = pgenB[s * M + m];
  const float scale = pg / Sv;
  float* orow = out + ((size_t)m * STEPS + s) * V;
#pragma unroll
  for (int j = 0; j < 6; ++j) {
    const int c = j * 512 + tid;
    if (c < V / 8) {
      f32x4 w0, w1;
#pragma unroll
      for (int e = 0; e < 4; ++e) {
        w0[e] = bf2f((u16)ch[j][e]) * scale;
        w1[e] = bf2f((u16)ch[j][4 + e]) * scale;
      }
      *(f32x4*)(orow + (size_t)c * 8) = w0;
      *(f32x4*)(orow + (size_t)c * 8 + 4) = w1;
    }
  }
  __syncthreads();
  const float om = 1.f - pg;
  for (int t = tid; t < T; t += 512) {
    float a = attnB[((size_t)s * M + m) * T + t];
    if (a != 0.f) atomicAdd(orow + story[b * T + t], om * a);
  }
}

// ---------------- launch ----------------

extern "C" void kernel_launch(void* const* d_in, const int* in_sizes, int n_in,
                              void* d_out, int out_size, void* d_ws, size_t ws_size,
                              hipStream_t stream) {
  (void)in_sizes; (void)n_in; (void)out_size; (void)ws_size;
  const float* emb  = (const float*)d_in[0];
  const float* Wih  = (const float*)d_in[1];
  const float* Whh  = (const float*)d_in[2];
  const float* bih  = (const float*)d_in[3];
  const float* bhh  = (const float*)d_in[4];
  const float* Wr   = (const float*)d_in[5];
  const float* br   = (const float*)d_in[6];
  const float* Wg   = (const float*)d_in[7];
  const float* bg   = (const float*)d_in[8];
  const float* semb = (const float*)d_in[9];
  const float* ehid = (const float*)d_in[10];
  const float* enc  = (const float*)d_in[11];
  const int*   lens = (const int*)d_in[12];
  const int*   story= (const int*)d_in[13];
  const int*   tgt  = (const int*)d_in[14];
  float* out = (float*)d_out;

  char* w = (char*)d_ws;
  size_t off = 0;
  auto alloc = [&](size_t n) -> void* {
    void* p = w + off;
    off = (off + n + 255) & ~(size_t)255;
    return p;
  };
  u16* ebf    = (u16*)alloc((size_t)VP * KP * 2);
  u16* wihH   = (u16*)alloc((size_t)NWP * KP * 2);
  u16* wihL   = (u16*)alloc((size_t)NWP * KP * 2);
  u16* whhH   = (u16*)alloc((size_t)NWP * KP * 2);
  u16* whhL   = (u16*)alloc((size_t)NWP * KP * 2);
  u16* decH   = (u16*)alloc((size_t)STEPS * MP * KP * 2);
  u16* decL   = (u16*)alloc((size_t)STEPS * MP * KP * 2);
  float* dec  = (float*)alloc((size_t)STEPS * M * H * 4);
  float* h0F  = (float*)alloc((size_t)M * H * 4);
  u16* h0H    = (u16*)alloc((size_t)MP * KP * 2);
  u16* h0L    = (u16*)alloc((size_t)MP * KP * 2);
  u16* hAllH  = (u16*)alloc((size_t)MR * KP * 2);
  u16* hAllL  = (u16*)alloc((size_t)MR * KP * 2);
  float* hallF= (float*)alloc((size_t)STEPS * M * H * 4);
  float* gi   = (float*)alloc((size_t)MR * H3 * 4);
  float* gh   = (float*)alloc((size_t)M * H3 * 4);
  float* attnB= (float*)alloc((size_t)STEPS * M * T * 4);
  float* pgenB= (float*)alloc((size_t)STEPS * M * 4);
  u16* ebuf   = (u16*)alloc((size_t)MR * VP * 2);
  u16* encbK  = (u16*)alloc((size_t)B * 400 * TPAD * 2);
  u16* encT   = (u16*)alloc((size_t)B * 400 * TPAD * 2);

  k_init<<<N_INIT, 256, 0, stream>>>(emb, enc, Wih, Whh, semb, ehid, tgt,
      ebf, encbK, encT, wihH, wihL, whhH, whhL, dec, decH, decL,
      h0F, h0H, h0L, hAllH, hAllL, ebuf);
  // all-steps gi = dec @ Wih^T + bih
  k_gemm64s<<<dim3(NCT, MR / 64), 256, 0, stream>>>(
      decH, decL, wihH, wihL, bih, gi, MR, H3, H3);

  // step 0 spine
  k_gemm64s<<<dim3(NCT, (M + 63) / 64), 256, 0, stream>>>(
      h0H, h0L, whhH, whhL, bhh, gh, M, H3, H3);
  k_cell<<<(M * H + 511) / 512, 512, 0, stream>>>(
      gi, gh, h0F, hallF, hAllH, hAllL);

  // steps 1..7: vocab(s-1) ∥ gh(s) in one launch, then cell(s)
  for (int s = 1; s < STEPS; ++s) {
    k_bigv<<<NVB_S + NGH, 512, 0, stream>>>(
        hAllH + (size_t)(s - 1) * MP * KP, hAllL + (size_t)(s - 1) * MP * KP,
        ebf, ebuf, (long long)(s - 1) * MP, whhH, whhL, bhh, gh);
    k_cell<<<(M * H + 511) / 512, 512, 0, stream>>>(
        gi + (size_t)s * MP * H3, gh, hallF + (size_t)(s - 1) * M * H,
        hallF + (size_t)s * M * H,
        hAllH + (size_t)s * MP * KP, hAllL + (size_t)s * MP * KP);
  }
  // tail: vocab(7) alone (grid has no gh blocks)
  k_bigv<<<NVB_S, 512, 0, stream>>>(
      hAllH + (size_t)7 * MP * KP, hAllL + (size_t)7 * MP * KP,
      ebf, ebuf, (long long)7 * MP, whhH, whhL, bhh, gh);

  // batched parallel phase
  k_attn<<<STEPS * B, 512, 0, stream>>>(hAllH, hAllL, hallF, encbK, encT, lens,
                                        dec, Wr, br, Wg, bg, attnB, pgenB, out);
  k_merge<<<STEPS * M, 512, 0, stream>>>(ebuf, pgenB, attnB, story, out);
}